// Round 9
// baseline (287.728 us; speedup 1.0000x reference)
//
#include <hip/hip_runtime.h>
#include <cstdint>
#include <cstddef>

typedef unsigned int u32;
typedef unsigned long long u64;

#define NBATCH 16
#define NA 9
#define HF 160
#define WF 160
#define HWC (HF*WF)          // 25600
#define NPB (NA*HWC)         // 230400 anchors per image
#define PRE_N 6000
#define POST_N 300
#define SEL_CAP 8192
#define NBIN 2048            // fallback radix bins
#define UNI_BINS 2048        // uniform score bins (2^11; s*2048 and q/2048 are exact fp32)
#define NMS_W 4              // waves in k_nms (256 threads; 8->4 halves barrier cost)

// Anchor constants derived exactly from generate_anchors(16,[0.5,1,2],[8,16,32]):
// all anchors have center (8,8) at cell (0,0); only w/h differ.
__constant__ float c_AW[9] = {184.f,368.f,736.f,128.f,256.f,512.f,88.f,176.f,352.f};
__constant__ float c_AH[9] = {96.f,192.f,384.f,128.f,256.f,512.f,176.f,352.f,704.f};

__device__ __forceinline__ void box_from_deltas(
    const float* __restrict__ bd, int b, int a, int pos,
    float imH, float imW, float ms,
    float& x1, float& y1, float& x2, float& y2, bool& keep)
{
  int y = pos / WF;
  int x = pos - y * WF;
  size_t base = ((size_t)(b * 4 * NA) + 4 * a) * HWC + (size_t)pos;
  float d0 = bd[base];
  float d1 = bd[base + HWC];
  float d2 = bd[base + 2 * HWC];
  float d3 = bd[base + 3 * HWC];
  float aw = c_AW[a], ah = c_AH[a];
  float acx = (float)x * 16.0f + 8.0f;
  float acy = (float)y * 16.0f + 8.0f;
  float pcx = d0 * aw + acx;
  float pcy = d1 * ah + acy;
  float pw  = expf(d2) * aw;
  float ph  = expf(d3) * ah;
  x1 = fminf(fmaxf(pcx - 0.5f * pw, 0.0f), imW - 1.0f);
  y1 = fminf(fmaxf(pcy - 0.5f * ph, 0.0f), imH - 1.0f);
  x2 = fminf(fmaxf(pcx + 0.5f * pw, 0.0f), imW - 1.0f);
  y2 = fminf(fmaxf(pcy + 0.5f * ph, 0.0f), imH - 1.0f);
  keep = ((x2 - x1 + 1.0f) >= ms) && ((y2 - y1 + 1.0f) >= ms);
}

__device__ __forceinline__ u32 desc_enc(float s) {
  u32 su = __float_as_uint(s);
  u32 asc = (su & 0x80000000u) ? ~su : (su | 0x80000000u);
  return ~asc;
}

// Exact divide-free IoU>0.7 test: fmaf sign is exact outside a relative 1e-6
// band; inside the band fall back to the IEEE divide (same operand order as
// the reference), so the decision is bit-identical to the reference.
__device__ __forceinline__ bool iou_gt(float inter, float uni) {
  float ss = fmaf(0.7f, uni, -inter);
  if (fabsf(ss) <= uni * 1e-6f) return (inter / uni > 0.7f);
  return ss < 0.0f;
}

// score -> order-flipped code + uniform bin (same mapping as prior rounds).
__device__ __forceinline__ u32 score_code(float s,
    float d0, float d1, float d2, float d3,
    float aw, float ah, float acx, float acy,
    float imH, float imW, float ms, int* bin) {
  float pcx = d0 * aw + acx;
  float pcy = d1 * ah + acy;
  float pw  = expf(d2) * aw;
  float ph  = expf(d3) * ah;
  float x1 = fminf(fmaxf(pcx - 0.5f * pw, 0.0f), imW - 1.0f);
  float y1 = fminf(fmaxf(pcy - 0.5f * ph, 0.0f), imH - 1.0f);
  float x2 = fminf(fmaxf(pcx + 0.5f * pw, 0.0f), imW - 1.0f);
  float y2 = fminf(fmaxf(pcy + 0.5f * ph, 0.0f), imH - 1.0f);
  bool keep = ((x2 - x1 + 1.0f) >= ms) && ((y2 - y1 + 1.0f) >= ms);
  if (!keep) s = __uint_as_float(0xFF800000u);  // -inf
  int q = (int)floorf(s * (float)UNI_BINS);
  q = q < 0 ? 0 : (q > UNI_BINS - 1 ? UNI_BINS - 1 : q);
  *bin = (UNI_BINS - 1) - q;
  return desc_enc(s);
}

// Block-wide inclusive scan of one u32 per thread: wave shfl scan + 1 barrier
// (replaces the 17-barrier Hillis-Steele). Caller must ensure a barrier between
// successive calls that reuse wsum.
__device__ __forceinline__ u32 block_scan_incl(u32 v, u32* wsum, int tid) {
  int lane = tid & 63, w = tid >> 6;
  u32 p = v;
  #pragma unroll
  for (int d = 1; d < 64; d <<= 1) {
    u32 t = __shfl_up(p, d);
    if (lane >= d) p += t;
  }
  if (lane == 63) wsum[w] = p;
  __syncthreads();
  u32 base = 0;
  for (int i = 0; i < w; i++) base += wsum[i];
  return base + p;
}

// u32 score codes (14.7 MB, half of u64 keys) + single-pass uniform histogram.
// 2-wide vectorized: float2 loads on all 5 streams, uint2 key store.
// Tie-break index i = pos*9 + a is recomputed downstream from linear position.
__global__ void __launch_bounds__(256) k_scores_hist(
    const float* __restrict__ sm, const float* __restrict__ bd,
    const float* __restrict__ info, u32* __restrict__ hkeys, u32* __restrict__ hist) {
  __shared__ u32 lh[UNI_BINS];
  int img = blockIdx.x / 30;
  int slice = blockIdx.x % 30;
  int tid = threadIdx.x;
  for (int i = tid; i < UNI_BINS; i += 256) lh[i] = 0;
  __syncthreads();
  float imH = info[img*3+0], imW = info[img*3+1], ms = 16.0f * info[img*3+2];
  for (int j = 0; j < 15; j++) {
    int t = (slice * 3840 + j * 256 + tid) * 2;   // even; pair stays in one channel/row
    int a = t / HWC;
    int pos = t - a * HWC;
    int y = pos / WF;
    int x = pos - y * WF;                          // even, <=158: x+1 never wraps
    const float2 s2 = *(const float2*)(sm + ((size_t)(img * 2 * NA) + NA + a) * HWC + pos);
    size_t base = ((size_t)(img * 4 * NA) + 4 * a) * HWC + (size_t)pos;
    float2 d0 = *(const float2*)(bd + base);
    float2 d1 = *(const float2*)(bd + base + HWC);
    float2 d2 = *(const float2*)(bd + base + 2 * HWC);
    float2 d3 = *(const float2*)(bd + base + 3 * HWC);
    float aw = c_AW[a], ah = c_AH[a];
    float acx = (float)x * 16.0f + 8.0f;
    float acy = (float)y * 16.0f + 8.0f;
    int b0, b1;
    u32 k0 = score_code(s2.x, d0.x, d1.x, d2.x, d3.x, aw, ah, acx,         acy, imH, imW, ms, &b0);
    u32 k1 = score_code(s2.y, d0.y, d1.y, d2.y, d3.y, aw, ah, acx + 16.0f, acy, imH, imW, ms, &b1);
    *(uint2*)(hkeys + (size_t)img * NPB + t) = make_uint2(k0, k1);
    atomicAdd(&lh[b0], 1u);
    atomicAdd(&lh[b1], 1u);
  }
  __syncthreads();
  u32* gh = hist + img * UNI_BINS;
  for (int i = tid; i < UNI_BINS; i += 256) { u32 v = lh[i]; if (v) atomicAdd(&gh[i], v); }
}

// Fused select + compact + box decode. Every block redundantly derives the
// threshold from the tiny L2-hot hist via a cheap shfl-scan (1 barrier — the
// 17-barrier version made r5's fusion a wash). Exact radix fallback kept for
// pathological ties (no-op on benign data). One atomicAdd per block.
// Sort element: [desc:32 (bits 62..31) | anchoridx:18 (30..13) | slot:13 (12..0)].
__global__ void __launch_bounds__(256) k_compactsel(
    const u32* __restrict__ hkeys, const u32* __restrict__ hist,
    u32* __restrict__ selcnt, u64* __restrict__ sel,
    const float* __restrict__ bd, const float* __restrict__ info,
    float4* __restrict__ boxsel) {
  int img = blockIdx.y;
  int tid = threadIdx.x;
  __shared__ u32 wsum[4];
  __shared__ u32 sc[256];
  __shared__ u32 lh[NBIN];
  __shared__ u64 sh_thresh;
  __shared__ int sh_state;
  __shared__ u64 sh_prefix;
  __shared__ u32 sh_kth;
  __shared__ u32 sbase;
  // ---- select: fast path from uniform hist ----
  {
    const u32* gh = hist + img * UNI_BINS;
    u32 loc[8]; u32 tot = 0;
    for (int j = 0; j < 8; j++) { loc[j] = gh[tid * 8 + j]; tot += loc[j]; }
    if (tid == 0) { sh_state = 0; sh_prefix = 0; sh_kth = PRE_N; }
    u32 incl = block_scan_incl(tot, wsum, tid);
    u32 excl = incl - tot;
    if (PRE_N > excl && PRE_N <= incl) {
      u32 run = excl;
      for (int j = 0; j < 8; j++) {
        run += loc[j];
        if (run >= PRE_N) {
          int b = tid * 8 + j;
          if (b < UNI_BINS - 1 && run <= SEL_CAP) {
            float sb = (float)(UNI_BINS - 1 - b) * (1.0f / (float)UNI_BINS);
            sh_thresh = ((u64)desc_enc(sb) << 32) | 0xFFFFFFFFull;
            sh_state = 1;
          }
          break;
        }
      }
    }
    __syncthreads();
  }
  // ---- exact radix fallback (rare; redundant per block) ----
  if (!sh_state) {
    const u32* hk = hkeys + (size_t)img * NPB;
    const int shifts[6] = {53, 42, 31, 20, 9, 0};
    const int widths[6] = {11, 11, 11, 11, 11, 9};
    for (int p = 0; p < 6; p++) {
      if (sh_state) break;
      for (int i = tid; i < NBIN; i += 256) lh[i] = 0;
      __syncthreads();
      u64 prefix = sh_prefix; u32 kth = sh_kth;
      int shift = shifts[p], width = widths[p];
      u32 nb = 1u << width;
      int hs = shift + width;
      for (int i = tid; i < NPB; i += 256) {
        int a = i / HWC; int pos = i - a * HWC;
        u64 key = ((u64)hk[i] << 32) | (u64)(u32)(pos * NA + a);
        bool m = (p == 0) || ((key >> hs) == prefix);
        if (m) atomicAdd(&lh[(u32)(key >> shift) & (nb - 1u)], 1u);
      }
      __syncthreads();
      u32 l2[8]; u32 t2 = 0;
      for (int j = 0; j < 8; j++) {
        u32 b = (u32)(tid * 8 + j);
        u32 v = (b < nb) ? lh[b] : 0u;
        l2[j] = v; t2 += v;
      }
      sc[tid] = t2; __syncthreads();
      for (int off = 1; off < 256; off <<= 1) {
        u32 v = sc[tid]; u32 a = (tid >= off) ? sc[tid - off] : 0u;
        __syncthreads(); sc[tid] = v + a; __syncthreads();
      }
      u32 incl2 = sc[tid], excl2 = incl2 - t2;
      if (kth > excl2 && kth <= incl2) {
        u32 run = excl2;
        for (int j = 0; j < 8; j++) {
          run += l2[j];
          if (run >= kth) {
            u32 bin = (u32)(tid * 8 + j);
            u32 below = run - l2[j];
            u32 cnt = l2[j];
            u32 knew = kth - below;
            u64 pfull = (prefix << width) | (u64)bin;
            u32 M = (u32)PRE_N - knew + cnt;
            if (M <= SEL_CAP) {
              u64 lowmask = (shift > 0) ? ((1ULL << shift) - 1ULL) : 0ULL;
              sh_thresh = (pfull << shift) | lowmask;
              sh_state = 1;
            } else {
              sh_prefix = pfull; sh_kth = knew;
            }
            break;
          }
        }
      }
      __syncthreads();
    }
  }
  u64 T = sh_thresh;
  // ---- compact sweep (shfl scan, 1 barrier) ----
  const u32* hp = hkeys + (size_t)img * NPB + (size_t)blockIdx.x * 3840;
  u32 mycnt = 0;
  #pragma unroll
  for (int j = 0; j < 15; j++) {
    int t = blockIdx.x * 3840 + j * 256 + tid;
    int a = t / HWC; int pos = t - a * HWC;
    u64 key = ((u64)hp[j * 256 + tid] << 32) | (u64)(u32)(pos * NA + a);
    if (key <= T) mycnt++;
  }
  u32 incl = block_scan_incl(mycnt, wsum, tid);
  if (tid == 255 && incl > 0) sbase = atomicAdd(&selcnt[img], incl);
  __syncthreads();
  if (mycnt == 0) return;
  u32 myoff = sbase + incl - mycnt;
  u64* sp = sel + (size_t)img * SEL_CAP;
  float4* bp = boxsel + (size_t)img * SEL_CAP;
  float imH = info[img*3+0], imW = info[img*3+1], ms = 16.0f * info[img*3+2];
  u32 c = 0;
  #pragma unroll
  for (int j = 0; j < 15; j++) {
    int t = blockIdx.x * 3840 + j * 256 + tid;
    int a = t / HWC; int pos = t - a * HWC;
    u32 idx = (u32)(pos * NA + a);
    u32 dsc = hp[j * 256 + tid];
    u64 key = ((u64)dsc << 32) | (u64)idx;
    if (key <= T) {
      u32 p = myoff + c;
      if (p < SEL_CAP) {
        sp[p] = ((u64)dsc << 31) | ((u64)idx << 13) | (u64)p;
        float x1, y1, x2, y2; bool keep;
        box_from_deltas(bd, img, a, pos, imH, imW, ms, x1, y1, x2, y2, keep);
        bp[p] = make_float4(x1, y1, x2, y2);
      }
      c++;
    }
  }
}

// Stage 1: sort each 1024-key chunk ascending in LDS (8 chunks/image x 16 images
// = 128 blocks -> full-chip parallelism for the 55 bitonic phases).
__global__ void __launch_bounds__(256) k_sort1(u64* __restrict__ sel, const u32* __restrict__ selcnt) {
  __shared__ u64 s[1024];
  int img = blockIdx.y, c = blockIdx.x, tid = threadIdx.x;
  u32 cnt = selcnt[img]; if (cnt > SEL_CAP) cnt = SEL_CAP;
  u64* sp = sel + (size_t)img * SEL_CAP + (size_t)c * 1024;
  int gbase = c * 1024;
  for (int i = tid; i < 1024; i += 256) s[i] = ((u32)(gbase + i) < cnt) ? sp[i] : ~0ULL;
  __syncthreads();
  for (int k = 2; k <= 1024; k <<= 1) {
    for (int j = k >> 1; j > 0; j >>= 1) {
      for (int i = tid; i < 1024; i += 256) {
        int p = i ^ j;
        if (p > i) {
          u64 a = s[i], b = s[p];
          bool up = ((i & k) == 0);
          if (up ? (a > b) : (a < b)) { s[i] = b; s[p] = a; }
        }
      }
      __syncthreads();
    }
  }
  for (int i = tid; i < 1024; i += 256) sp[i] = s[i];
}

// Stage 2: merge 8 sorted 1024-runs -> 8192 via 3 merge-path levels (6 barriers).
// Epilogue: rank -> slot -> boxsel gather (128 KB/img, L2-resident) + validity.
__global__ void __launch_bounds__(1024) k_sort2(
    const u64* __restrict__ sel, const float4* __restrict__ boxsel,
    float4* __restrict__ boxes, u32* __restrict__ nvalid) {
  __shared__ u64 s[SEL_CAP];   // 64 KiB
  __shared__ int sh_nv;
  int img = blockIdx.x;
  int tid = threadIdx.x;
  const u64* sp = sel + (size_t)img * SEL_CAP;
  if (tid == 0) sh_nv = PRE_N;
  for (int i = tid; i < SEL_CAP; i += 1024) s[i] = sp[i];
  __syncthreads();
  int d0 = tid * 8;
  for (int L = 1024; L < SEL_CAP; L <<= 1) {
    int pairBase = d0 & ~(2 * L - 1);
    int d = d0 - pairBase;
    const u64* A = s + pairBase;
    const u64* B = s + pairBase + L;
    int lo = d - L; if (lo < 0) lo = 0;
    int hi = (d < L) ? d : L;
    while (lo < hi) {
      int mid = (lo + hi) >> 1;
      if (A[mid] <= B[d - 1 - mid]) lo = mid + 1; else hi = mid;
    }
    int ia = lo, ib = d - lo;
    u64 o[8];
    #pragma unroll
    for (int k = 0; k < 8; k++) {
      bool ta = (ib >= L) || (ia < L && A[ia] <= B[ib]);
      o[k] = ta ? A[ia++] : B[ib++];
    }
    __syncthreads();
    #pragma unroll
    for (int k = 0; k < 8; k++) s[d0 + k] = o[k];
    __syncthreads();
  }
  const float4* bp = boxsel + (size_t)img * SEL_CAP;
  for (int r = tid; r < PRE_N; r += 1024) {
    u64 key = s[r];
    u32 desc = (u32)(key >> 31);               // for padding ~0 this is 0xFFFFFFFF
    bool valid = desc < 0xFF800000u;           // score > -inf
    if (!valid) atomicMin(&sh_nv, r);
    float4 bx = valid ? bp[key & 0x1FFFu] : make_float4(0.f, 0.f, 0.f, 0.f);
    boxes[(size_t)img * PRE_N + r] = bx;
  }
  __syncthreads();
  if (tid == 0) nvalid[img] = (u32)sh_nv;
}

// NMS: r8 structure (BQ=64, double-buffered, column-mask serial phase) at 256
// threads / 4 waves — halves the per-round barrier cost that dominates the
// 94-round loop. Work split per wave doubles but stays latency-hidden.
__global__ void __launch_bounds__(256) k_nms(const float4* __restrict__ boxes,
                                             const u32* __restrict__ nvalid_arr,
                                             float* __restrict__ out) {
  __shared__ float4 kbox[POST_N];
  __shared__ float karea[POST_N];
  __shared__ u64 kcodeW[(POST_N + 7) / 8];
  __shared__ float4 cb[2][64];
  __shared__ float car[2][64];
  __shared__ int cint[2][64];
  __shared__ u64 wcol[2][64];              // column masks: bit i of wcol[j] => i suppresses j
  __shared__ u64 supw[2][NMS_W];
  __shared__ int sh_nkept;
  int img = blockIdx.x;
  int tid = threadIdx.x;
  int lane = tid & 63;
  int wv = tid >> 6;
  int nvalid = (int)nvalid_arr[img];
  if (nvalid > PRE_N) nvalid = PRE_N;
  const float4* bb = boxes + (size_t)img * PRE_N;
  if (tid == 0) sh_nkept = 0;
  if (tid < 64) {
    float4 c = (tid < nvalid) ? bb[tid] : make_float4(0.f, 0.f, 0.f, 0.f);
    cb[0][tid] = c;
    float A = (c.z - c.x + 1.0f) * (c.w - c.y + 1.0f);
    car[0][tid] = A;
    cint[0][tid] = (int)rintf(8.0f * log2f(A));
  } else if (tid < 128) {
    wcol[0][tid - 64] = 0;
  } else if (tid < 128 + NMS_W) {
    supw[0][tid - 128] = 0;
  }
  __syncthreads();
  int pb = 0;
  for (int base = 0; base < nvalid; base += 64, pb ^= 1) {
    int nk = sh_nkept;
    if (nk >= POST_N) break;
    int bn = nvalid - base; if (bn > 64) bn = 64;
    // ---- phase A: vs-kept tests + within-batch column masks ----
    bool sup;
    u64 colpart = 0;
    {
      bool inb = lane < bn;
      sup = !inb;
      if (inb) {
        float4 C = cb[pb][lane];
        float A0 = car[pb][lane];
        int myc = cint[pb][lane];
        int nw = (nk + 7) >> 3;
        for (int jw = wv; jw < nw && !sup; jw += NMS_W) {
          u64 w = kcodeW[jw];
          int jbase = jw << 3;
          int jm = nk - jbase; if (jm > 8) jm = 8;
          for (int k = 0; k < jm; k++) {
            int d = (int)((w >> (k * 8)) & 0xFFu) - myc;
            if (d > 5 || d < -5) continue;          // conservative area-ratio gate
            int j = jbase + k;
            float4 K = kbox[j];
            float xx1 = fmaxf(K.x, C.x);
            float yy1 = fmaxf(K.y, C.y);
            float xx2 = fminf(K.z, C.z);
            float yy2 = fminf(K.w, C.w);
            float iw = fmaxf(0.0f, xx2 - xx1 + 1.0f);
            float ih = fmaxf(0.0f, yy2 - yy1 + 1.0f);
            float inter = iw * ih;
            float uni = (karea[j] + A0) - inter;    // kept area first (ref order)
            if (iou_gt(inter, uni)) { sup = true; break; }
          }
        }
        // within-batch: candidate = lane (the LATER one), scan earlier i
        for (int i = wv; i < lane; i += NMS_W) {
          if (i >= bn) break;
          float Ai = car[pb][i];
          if (Ai <= 0.6999f * A0 || A0 <= 0.6999f * Ai) continue;
          float4 I4 = cb[pb][i];
          float xx1 = fmaxf(I4.x, C.x);
          float yy1 = fmaxf(I4.y, C.y);
          float xx2 = fminf(I4.z, C.z);
          float yy2 = fminf(I4.w, C.w);
          float iw = fmaxf(0.0f, xx2 - xx1 + 1.0f);
          float ih = fmaxf(0.0f, yy2 - yy1 + 1.0f);
          float inter = iw * ih;
          float uni = (Ai + A0) - inter;            // earlier (i) area first
          if (iou_gt(inter, uni)) colpart |= 1ULL << i;
        }
      }
    }
    u64 bm = __ballot(sup);
    if (lane == 0) supw[pb][wv] = bm;
    if (colpart) atomicOr(&wcol[pb][lane], colpart);
    __syncthreads();
    // ---- phase B (wave 0: serial greedy via ballot) | prefetch (waves 1-2) ----
    if (wv == 0) {
      u64 so = (lane < NMS_W) ? supw[pb][lane] : 0ULL;
      so |= __shfl_xor(so, 1);
      so |= __shfl_xor(so, 2);
      so = __shfl(so, 0);
      u64 validm = (bn >= 64) ? ~0ULL : ((1ULL << bn) - 1ULL);
      u64 colm = wcol[pb][lane];                 // who suppresses ME (earlier-only bits)
      u64 live = validm & ~so;
      u64 km = 0;
      int cnt = nk;
      while (live && cnt < POST_N) {
        int c = __ffsll((long long)live) - 1;
        km |= 1ULL << c;
        cnt++;
        u64 dead = __ballot((colm >> c) & 1ULL);   // lanes suppressed by keep c
        live &= ~dead;
        live &= ~(1ULL << c);
      }
      if ((km >> lane) & 1ULL) {
        int rank = nk + (int)__popcll(km & ((1ULL << lane) - 1ULL));
        float4 C = cb[pb][lane];
        kbox[rank] = C;
        karea[rank] = car[pb][lane];
        ((unsigned char*)kcodeW)[rank] = (unsigned char)cint[pb][lane];
        float* o = out + ((size_t)img * POST_N + rank) * 5;
        o[0] = (float)img; o[1] = C.x; o[2] = C.y; o[3] = C.z; o[4] = C.w;
      }
      if (lane == 0) sh_nkept = cnt;
    } else if (wv == 1) {
      int nb2 = base + 64;
      if (nb2 < nvalid) {
        int i = nb2 + lane;
        float4 c = (i < nvalid) ? bb[i] : make_float4(0.f, 0.f, 0.f, 0.f);
        cb[pb ^ 1][lane] = c;
        float A = (c.z - c.x + 1.0f) * (c.w - c.y + 1.0f);
        car[pb ^ 1][lane] = A;
        cint[pb ^ 1][lane] = (int)rintf(8.0f * log2f(A));
      }
    } else if (wv == 2) {
      wcol[pb ^ 1][lane] = 0;
      if (lane < NMS_W) supw[pb ^ 1][lane] = 0;
    }
    __syncthreads();
  }
  int fk = sh_nkept;
  for (int r = fk + tid; r < POST_N; r += 256) {
    float* o = out + ((size_t)img * POST_N + r) * 5;
    o[0] = (float)img; o[1] = 0.f; o[2] = 0.f; o[3] = 0.f; o[4] = 0.f;
  }
}

extern "C" void kernel_launch(void* const* d_in, const int* in_sizes, int n_in,
                              void* d_out, int out_size, void* d_ws, size_t ws_size,
                              hipStream_t stream) {
  const float* sm   = (const float*)d_in[0];
  const float* bd   = (const float*)d_in[1];
  const float* info = (const float*)d_in[2];
  float* out = (float*)d_out;
  char* ws = (char*)d_ws;

  size_t off = 0;
  auto alloc = [&](size_t bytes) { size_t o = off; off += (bytes + 255) & ~(size_t)255; return o; };
  u32* hkeys    = (u32*)(ws + alloc((size_t)NBATCH * NPB * 4));        // 14.7 MB
  size_t off_hist = alloc((size_t)NBATCH * UNI_BINS * 4);              // 128 KB
  u32* hist     = (u32*)(ws + off_hist);
  u32* selcnt   = (u32*)(ws + alloc(NBATCH * 4));                      // adjacent to hist
  size_t zero_end = off;
  u32* nvalid   = (u32*)(ws + alloc(NBATCH * 4));
  u64* sel      = (u64*)(ws + alloc((size_t)NBATCH * SEL_CAP * 8));    // 1 MB
  float4* boxsel= (float4*)(ws + alloc((size_t)NBATCH * SEL_CAP * 16));// 2 MB
  float4* boxes = (float4*)(ws + alloc((size_t)NBATCH * PRE_N * 16));  // 1.5 MB
  (void)ws_size; (void)in_sizes; (void)n_in; (void)out_size;

  hipMemsetAsync(ws + off_hist, 0, zero_end - off_hist, stream);       // hist + selcnt
  hipLaunchKernelGGL(k_scores_hist, dim3(480), dim3(256), 0, stream, sm, bd, info, hkeys, hist);
  hipLaunchKernelGGL(k_compactsel, dim3(60, 16), dim3(256), 0, stream,
                     hkeys, hist, selcnt, sel, bd, info, boxsel);
  hipLaunchKernelGGL(k_sort1, dim3(8, 16), dim3(256), 0, stream, sel, selcnt);
  hipLaunchKernelGGL(k_sort2, dim3(16), dim3(1024), 0, stream, sel, boxsel, boxes, nvalid);
  hipLaunchKernelGGL(k_nms, dim3(16), dim3(256), 0, stream, boxes, nvalid, out);
}

// Round 10
// 246.957 us; speedup vs baseline: 1.1651x; 1.1651x over previous
//
#include <hip/hip_runtime.h>
#include <cstdint>
#include <cstddef>

typedef unsigned int u32;
typedef unsigned long long u64;

#define NBATCH 16
#define NA 9
#define HF 160
#define WF 160
#define HWC (HF*WF)          // 25600
#define NPB (NA*HWC)         // 230400 anchors per image
#define PRE_N 6000
#define POST_N 300
#define SEL_CAP 8192
#define NBIN 2048            // fallback radix bins
#define UNI_BINS 2048        // uniform score bins (2^11; s*2048 and q/2048 are exact fp32)
#define NMS_W 8              // waves in k_nms (512 threads; r9 showed 4 waves regresses)

// Anchor constants derived exactly from generate_anchors(16,[0.5,1,2],[8,16,32]):
// all anchors have center (8,8) at cell (0,0); only w/h differ.
__constant__ float c_AW[9] = {184.f,368.f,736.f,128.f,256.f,512.f,88.f,176.f,352.f};
__constant__ float c_AH[9] = {96.f,192.f,384.f,128.f,256.f,512.f,176.f,352.f,704.f};

__device__ __forceinline__ void box_from_deltas(
    const float* __restrict__ bd, int b, int a, int pos,
    float imH, float imW, float ms,
    float& x1, float& y1, float& x2, float& y2, bool& keep)
{
  int y = pos / WF;
  int x = pos - y * WF;
  size_t base = ((size_t)(b * 4 * NA) + 4 * a) * HWC + (size_t)pos;
  float d0 = bd[base];
  float d1 = bd[base + HWC];
  float d2 = bd[base + 2 * HWC];
  float d3 = bd[base + 3 * HWC];
  float aw = c_AW[a], ah = c_AH[a];
  float acx = (float)x * 16.0f + 8.0f;
  float acy = (float)y * 16.0f + 8.0f;
  float pcx = d0 * aw + acx;
  float pcy = d1 * ah + acy;
  float pw  = expf(d2) * aw;
  float ph  = expf(d3) * ah;
  x1 = fminf(fmaxf(pcx - 0.5f * pw, 0.0f), imW - 1.0f);
  y1 = fminf(fmaxf(pcy - 0.5f * ph, 0.0f), imH - 1.0f);
  x2 = fminf(fmaxf(pcx + 0.5f * pw, 0.0f), imW - 1.0f);
  y2 = fminf(fmaxf(pcy + 0.5f * ph, 0.0f), imH - 1.0f);
  keep = ((x2 - x1 + 1.0f) >= ms) && ((y2 - y1 + 1.0f) >= ms);
}

__device__ __forceinline__ u32 desc_enc(float s) {
  u32 su = __float_as_uint(s);
  u32 asc = (su & 0x80000000u) ? ~su : (su | 0x80000000u);
  return ~asc;
}

// Exact divide-free IoU>0.7 test: fmaf sign is exact outside a relative 1e-6
// band; inside the band fall back to the IEEE divide (same operand order as
// the reference), so the decision is bit-identical to the reference.
__device__ __forceinline__ bool iou_gt(float inter, float uni) {
  float ss = fmaf(0.7f, uni, -inter);
  if (fabsf(ss) <= uni * 1e-6f) return (inter / uni > 0.7f);
  return ss < 0.0f;
}

// keys + single-pass uniform-bin histogram (fused).
// Key: high 32 = order-flipped score (descending), low 32 = reference flat index
// i = pos*9 + a -> ascending u64 order == stable top_k order. Bin: 2047 - floor(s*2048)
// (exact fp32 mapping; -inf -> cvt saturates negative -> bin 2047).
__global__ void __launch_bounds__(256) k_scores_hist(
    const float* __restrict__ sm, const float* __restrict__ bd,
    const float* __restrict__ info, u64* __restrict__ keys, u32* __restrict__ hist) {
  __shared__ u32 lh[UNI_BINS];
  int img = blockIdx.x / 60;
  int slice = blockIdx.x % 60;
  int tid = threadIdx.x;
  for (int i = tid; i < UNI_BINS; i += 256) lh[i] = 0;
  __syncthreads();
  float imH = info[img*3+0], imW = info[img*3+1], ms = 16.0f * info[img*3+2];
  for (int j = 0; j < 15; j++) {
    int t = slice * 3840 + j * 256 + tid;
    int a = t / HWC;
    int pos = t - a * HWC;
    float s = sm[((size_t)(img * 2 * NA) + NA + a) * HWC + (size_t)pos];
    float x1, y1, x2, y2; bool keep;
    box_from_deltas(bd, img, a, pos, imH, imW, ms, x1, y1, x2, y2, keep);
    if (!keep) s = __uint_as_float(0xFF800000u);  // -inf
    u32 idx = (u32)(pos * NA + a);
    keys[(size_t)img * NPB + t] = ((u64)desc_enc(s) << 32) | (u64)idx;
    int q = (int)floorf(s * (float)UNI_BINS);
    q = q < 0 ? 0 : (q > UNI_BINS - 1 ? UNI_BINS - 1 : q);
    atomicAdd(&lh[(UNI_BINS - 1) - q], 1u);
  }
  __syncthreads();
  u32* gh = hist + img * UNI_BINS;
  for (int i = tid; i < UNI_BINS; i += 256) { u32 v = lh[i]; if (v) atomicAdd(&gh[i], v); }
}

// Select threshold from the uniform hist (1 pass, exact). If the boundary bin
// would overflow SEL_CAP or sits in the -inf bin, run an exact in-block 6-pass
// radix fallback (pathological-tie insurance; no-op on benign data).
__global__ void __launch_bounds__(256) k_select(
    const u64* __restrict__ keys, const u32* __restrict__ hist, u64* __restrict__ thresh_arr) {
  int img = blockIdx.x, tid = threadIdx.x;
  __shared__ u32 sc[256];
  __shared__ u32 lh[NBIN];
  __shared__ u64 sh_thresh;
  __shared__ int sh_state;
  __shared__ u64 sh_prefix;
  __shared__ u32 sh_kth;
  const u32* gh = hist + img * UNI_BINS;
  u32 loc[8]; u32 tot = 0;
  for (int j = 0; j < 8; j++) { loc[j] = gh[tid * 8 + j]; tot += loc[j]; }
  if (tid == 0) { sh_state = 0; sh_prefix = 0; sh_kth = PRE_N; }
  sc[tid] = tot;
  __syncthreads();
  for (int off = 1; off < 256; off <<= 1) {
    u32 v = sc[tid]; u32 a = (tid >= off) ? sc[tid - off] : 0u;
    __syncthreads(); sc[tid] = v + a; __syncthreads();
  }
  u32 incl = sc[tid], excl = incl - tot;
  if (PRE_N > excl && PRE_N <= incl) {
    u32 run = excl;
    for (int j = 0; j < 8; j++) {
      run += loc[j];
      if (run >= PRE_N) {
        int b = tid * 8 + j;
        if (b < UNI_BINS - 1 && run <= SEL_CAP) {
          float sb = (float)(UNI_BINS - 1 - b) * (1.0f / (float)UNI_BINS);
          sh_thresh = ((u64)desc_enc(sb) << 32) | 0xFFFFFFFFull;
          sh_state = 1;
        }
        break;
      }
    }
  }
  __syncthreads();
  if (!sh_state) {
    const u64* kp = keys + (size_t)img * NPB;
    const int shifts[6] = {53, 42, 31, 20, 9, 0};
    const int widths[6] = {11, 11, 11, 11, 11, 9};
    for (int p = 0; p < 6; p++) {
      if (sh_state) break;
      for (int i = tid; i < NBIN; i += 256) lh[i] = 0;
      __syncthreads();
      u64 prefix = sh_prefix; u32 kth = sh_kth;
      int shift = shifts[p], width = widths[p];
      u32 nb = 1u << width;
      int hs = shift + width;
      for (int i = tid; i < NPB; i += 256) {
        u64 key = kp[i];
        bool m = (p == 0) || ((key >> hs) == prefix);
        if (m) atomicAdd(&lh[(u32)(key >> shift) & (nb - 1u)], 1u);
      }
      __syncthreads();
      u32 l2[8]; u32 t2 = 0;
      for (int j = 0; j < 8; j++) {
        u32 b = (u32)(tid * 8 + j);
        u32 v = (b < nb) ? lh[b] : 0u;
        l2[j] = v; t2 += v;
      }
      sc[tid] = t2; __syncthreads();
      for (int off = 1; off < 256; off <<= 1) {
        u32 v = sc[tid]; u32 a = (tid >= off) ? sc[tid - off] : 0u;
        __syncthreads(); sc[tid] = v + a; __syncthreads();
      }
      u32 incl2 = sc[tid], excl2 = incl2 - t2;
      if (kth > excl2 && kth <= incl2) {
        u32 run = excl2;
        for (int j = 0; j < 8; j++) {
          run += l2[j];
          if (run >= kth) {
            u32 bin = (u32)(tid * 8 + j);
            u32 below = run - l2[j];
            u32 cnt = l2[j];
            u32 knew = kth - below;
            u64 pfull = (prefix << width) | (u64)bin;
            u32 M = (u32)PRE_N - knew + cnt;
            if (M <= SEL_CAP) {
              u64 lowmask = (shift > 0) ? ((1ULL << shift) - 1ULL) : 0ULL;
              sh_thresh = (pfull << shift) | lowmask;
              sh_state = 1;
            } else {
              sh_prefix = pfull; sh_kth = knew;
            }
            break;
          }
        }
      }
      __syncthreads();
    }
  }
  if (tid == 0) thresh_arr[img] = sh_thresh;
}

// Block-aggregated compaction + box decode for selected keys.
// Sort element: [desc:32 (bits 62..31) | anchoridx:18 (30..13) | slot:13 (12..0)].
__global__ void k_compact(const u64* __restrict__ keys, const u64* __restrict__ thresh,
                          u32* __restrict__ selcnt, u64* __restrict__ sel,
                          const float* __restrict__ bd, const float* __restrict__ info,
                          float4* __restrict__ boxsel) {
  int img = blockIdx.y;
  int tid = threadIdx.x;
  u64 T = thresh[img];
  const u64* kp = keys + (size_t)img * NPB + (size_t)blockIdx.x * 3840;
  u32 mycnt = 0;
  #pragma unroll
  for (int j = 0; j < 15; j++) {
    u64 key = kp[j * 256 + tid];
    if (key <= T) mycnt++;
  }
  __shared__ u32 sc[256];
  __shared__ u32 sbase;
  sc[tid] = mycnt;
  __syncthreads();
  for (int off = 1; off < 256; off <<= 1) {
    u32 v = sc[tid];
    u32 add = (tid >= off) ? sc[tid - off] : 0u;
    __syncthreads();
    sc[tid] = v + add;
    __syncthreads();
  }
  if (tid == 255 && sc[255] > 0) sbase = atomicAdd(&selcnt[img], sc[255]);
  __syncthreads();
  if (mycnt == 0) return;
  u32 myoff = sbase + sc[tid] - mycnt;
  u64* sp = sel + (size_t)img * SEL_CAP;
  float4* bp = boxsel + (size_t)img * SEL_CAP;
  float imH = info[img*3+0], imW = info[img*3+1], ms = 16.0f * info[img*3+2];
  u32 c = 0;
  #pragma unroll
  for (int j = 0; j < 15; j++) {
    u64 key = kp[j * 256 + tid];
    if (key <= T) {
      u32 p = myoff + c;
      if (p < SEL_CAP) {
        u32 desc = (u32)(key >> 32);
        u32 idx = (u32)key;
        sp[p] = ((u64)desc << 31) | ((u64)idx << 13) | (u64)p;
        int a = (int)(idx % NA);
        int pos = (int)(idx / NA);
        float x1, y1, x2, y2; bool keep;
        box_from_deltas(bd, img, a, pos, imH, imW, ms, x1, y1, x2, y2, keep);
        bp[p] = make_float4(x1, y1, x2, y2);
      }
      c++;
    }
  }
}

// Stage 1: sort each 1024-key chunk ascending in LDS (8 chunks/image x 16 images
// = 128 blocks -> full-chip parallelism for the 55 bitonic phases).
__global__ void __launch_bounds__(256) k_sort1(u64* __restrict__ sel, const u32* __restrict__ selcnt) {
  __shared__ u64 s[1024];
  int img = blockIdx.y, c = blockIdx.x, tid = threadIdx.x;
  u32 cnt = selcnt[img]; if (cnt > SEL_CAP) cnt = SEL_CAP;
  u64* sp = sel + (size_t)img * SEL_CAP + (size_t)c * 1024;
  int gbase = c * 1024;
  for (int i = tid; i < 1024; i += 256) s[i] = ((u32)(gbase + i) < cnt) ? sp[i] : ~0ULL;
  __syncthreads();
  for (int k = 2; k <= 1024; k <<= 1) {
    for (int j = k >> 1; j > 0; j >>= 1) {
      for (int i = tid; i < 1024; i += 256) {
        int p = i ^ j;
        if (p > i) {
          u64 a = s[i], b = s[p];
          bool up = ((i & k) == 0);
          if (up ? (a > b) : (a < b)) { s[i] = b; s[p] = a; }
        }
      }
      __syncthreads();
    }
  }
  for (int i = tid; i < 1024; i += 256) sp[i] = s[i];
}

// Stage 2: merge 8 sorted 1024-runs -> 8192 via 3 merge-path levels (6 barriers).
// Epilogue: rank -> slot -> boxsel gather (128 KB/img, L2-resident) + validity.
__global__ void __launch_bounds__(1024) k_sort2(
    const u64* __restrict__ sel, const float4* __restrict__ boxsel,
    float4* __restrict__ boxes, u32* __restrict__ nvalid) {
  __shared__ u64 s[SEL_CAP];   // 64 KiB
  __shared__ int sh_nv;
  int img = blockIdx.x;
  int tid = threadIdx.x;
  const u64* sp = sel + (size_t)img * SEL_CAP;
  if (tid == 0) sh_nv = PRE_N;
  for (int i = tid; i < SEL_CAP; i += 1024) s[i] = sp[i];
  __syncthreads();
  int d0 = tid * 8;
  for (int L = 1024; L < SEL_CAP; L <<= 1) {
    int pairBase = d0 & ~(2 * L - 1);
    int d = d0 - pairBase;
    const u64* A = s + pairBase;
    const u64* B = s + pairBase + L;
    int lo = d - L; if (lo < 0) lo = 0;
    int hi = (d < L) ? d : L;
    while (lo < hi) {
      int mid = (lo + hi) >> 1;
      if (A[mid] <= B[d - 1 - mid]) lo = mid + 1; else hi = mid;
    }
    int ia = lo, ib = d - lo;
    u64 o[8];
    #pragma unroll
    for (int k = 0; k < 8; k++) {
      bool ta = (ib >= L) || (ia < L && A[ia] <= B[ib]);
      o[k] = ta ? A[ia++] : B[ib++];
    }
    __syncthreads();
    #pragma unroll
    for (int k = 0; k < 8; k++) s[d0 + k] = o[k];
    __syncthreads();
  }
  const float4* bp = boxsel + (size_t)img * SEL_CAP;
  for (int r = tid; r < PRE_N; r += 1024) {
    u64 key = s[r];
    u32 desc = (u32)(key >> 31);               // for padding ~0 this is 0xFFFFFFFF
    bool valid = desc < 0xFF800000u;           // score > -inf
    if (!valid) atomicMin(&sh_nv, r);
    float4 bx = valid ? bp[key & 0x1FFFu] : make_float4(0.f, 0.f, 0.f, 0.f);
    boxes[(size_t)img * PRE_N + r] = bx;
  }
  __syncthreads();
  if (tid == 0) nvalid[img] = (u32)sh_nv;
}

// NMS (r8 structure: BQ=64, 512 threads, double-buffered, column-mask serial
// phase) with ONE change: phase A's kept-scan has NO early exit — `sup` is
// OR-accumulated. The `&& !sup` loop condition made each iteration's ds_read
// wait on the previous iteration's IoU (~120 cyc/link serialized, r9 evidence);
// without it the LDS loads are address-independent and pipeline. Decisions
// unchanged (OR is order-independent).
__global__ void __launch_bounds__(512) k_nms(const float4* __restrict__ boxes,
                                             const u32* __restrict__ nvalid_arr,
                                             float* __restrict__ out) {
  __shared__ float4 kbox[POST_N];
  __shared__ float karea[POST_N];
  __shared__ u64 kcodeW[(POST_N + 7) / 8];
  __shared__ float4 cb[2][64];
  __shared__ float car[2][64];
  __shared__ int cint[2][64];
  __shared__ u64 wcol[2][64];              // column masks: bit i of wcol[j] => i suppresses j
  __shared__ u64 supw[2][NMS_W];
  __shared__ int sh_nkept;
  int img = blockIdx.x;
  int tid = threadIdx.x;
  int lane = tid & 63;
  int wv = tid >> 6;
  int nvalid = (int)nvalid_arr[img];
  if (nvalid > PRE_N) nvalid = PRE_N;
  const float4* bb = boxes + (size_t)img * PRE_N;
  if (tid == 0) sh_nkept = 0;
  if (tid < 64) {
    float4 c = (tid < nvalid) ? bb[tid] : make_float4(0.f, 0.f, 0.f, 0.f);
    cb[0][tid] = c;
    float A = (c.z - c.x + 1.0f) * (c.w - c.y + 1.0f);
    car[0][tid] = A;
    cint[0][tid] = (int)rintf(8.0f * log2f(A));
  } else if (tid < 128) {
    wcol[0][tid - 64] = 0;
  } else if (tid < 128 + NMS_W) {
    supw[0][tid - 128] = 0;
  }
  __syncthreads();
  int pb = 0;
  for (int base = 0; base < nvalid; base += 64, pb ^= 1) {
    int nk = sh_nkept;
    if (nk >= POST_N) break;
    int bn = nvalid - base; if (bn > 64) bn = 64;
    // ---- phase A: vs-kept tests + within-batch column masks (no early exit) ----
    bool sup;
    u64 colpart = 0;
    {
      bool inb = lane < bn;
      sup = !inb;
      if (inb) {
        float4 C = cb[pb][lane];
        float A0 = car[pb][lane];
        int myc = cint[pb][lane];
        int nw = (nk + 7) >> 3;
        for (int jw = wv; jw < nw; jw += NMS_W) {
          u64 w = kcodeW[jw];
          int jbase = jw << 3;
          int jm = nk - jbase; if (jm > 8) jm = 8;
          for (int k = 0; k < jm; k++) {
            int d = (int)((w >> (k * 8)) & 0xFFu) - myc;
            if (d > 5 || d < -5) continue;          // conservative area-ratio gate
            int j = jbase + k;
            float4 K = kbox[j];
            float xx1 = fmaxf(K.x, C.x);
            float yy1 = fmaxf(K.y, C.y);
            float xx2 = fminf(K.z, C.z);
            float yy2 = fminf(K.w, C.w);
            float iw = fmaxf(0.0f, xx2 - xx1 + 1.0f);
            float ih = fmaxf(0.0f, yy2 - yy1 + 1.0f);
            float inter = iw * ih;
            float uni = (karea[j] + A0) - inter;    // kept area first (ref order)
            sup = sup | iou_gt(inter, uni);
          }
        }
        // within-batch: candidate = lane (the LATER one), scan earlier i
        for (int i = wv; i < lane; i += NMS_W) {
          if (i >= bn) break;
          float Ai = car[pb][i];
          if (Ai <= 0.6999f * A0 || A0 <= 0.6999f * Ai) continue;
          float4 I4 = cb[pb][i];
          float xx1 = fmaxf(I4.x, C.x);
          float yy1 = fmaxf(I4.y, C.y);
          float xx2 = fminf(I4.z, C.z);
          float yy2 = fminf(I4.w, C.w);
          float iw = fmaxf(0.0f, xx2 - xx1 + 1.0f);
          float ih = fmaxf(0.0f, yy2 - yy1 + 1.0f);
          float inter = iw * ih;
          float uni = (Ai + A0) - inter;            // earlier (i) area first
          if (iou_gt(inter, uni)) colpart |= 1ULL << i;
        }
      }
    }
    u64 bm = __ballot(sup);
    if (lane == 0) supw[pb][wv] = bm;
    if (colpart) atomicOr(&wcol[pb][lane], colpart);
    __syncthreads();
    // ---- phase B (wave 0: serial greedy via ballot) | prefetch (waves 1-2) ----
    if (wv == 0) {
      u64 so = (lane < NMS_W) ? supw[pb][lane] : 0ULL;
      so |= __shfl_xor(so, 1);
      so |= __shfl_xor(so, 2);
      so |= __shfl_xor(so, 4);
      so = __shfl(so, 0);
      u64 validm = (bn >= 64) ? ~0ULL : ((1ULL << bn) - 1ULL);
      u64 colm = wcol[pb][lane];                 // who suppresses ME (earlier-only bits)
      u64 live = validm & ~so;
      u64 km = 0;
      int cnt = nk;
      while (live && cnt < POST_N) {
        int c = __ffsll((long long)live) - 1;
        km |= 1ULL << c;
        cnt++;
        u64 dead = __ballot((colm >> c) & 1ULL);   // lanes suppressed by keep c
        live &= ~dead;
        live &= ~(1ULL << c);
      }
      if ((km >> lane) & 1ULL) {
        int rank = nk + (int)__popcll(km & ((1ULL << lane) - 1ULL));
        float4 C = cb[pb][lane];
        kbox[rank] = C;
        karea[rank] = car[pb][lane];
        ((unsigned char*)kcodeW)[rank] = (unsigned char)cint[pb][lane];
        float* o = out + ((size_t)img * POST_N + rank) * 5;
        o[0] = (float)img; o[1] = C.x; o[2] = C.y; o[3] = C.z; o[4] = C.w;
      }
      if (lane == 0) sh_nkept = cnt;
    } else if (wv == 1) {
      int nb2 = base + 64;
      if (nb2 < nvalid) {
        int i = nb2 + lane;
        float4 c = (i < nvalid) ? bb[i] : make_float4(0.f, 0.f, 0.f, 0.f);
        cb[pb ^ 1][lane] = c;
        float A = (c.z - c.x + 1.0f) * (c.w - c.y + 1.0f);
        car[pb ^ 1][lane] = A;
        cint[pb ^ 1][lane] = (int)rintf(8.0f * log2f(A));
      }
    } else if (wv == 2) {
      wcol[pb ^ 1][lane] = 0;
      if (lane < NMS_W) supw[pb ^ 1][lane] = 0;
    }
    __syncthreads();
  }
  int fk = sh_nkept;
  for (int r = fk + tid; r < POST_N; r += 512) {
    float* o = out + ((size_t)img * POST_N + r) * 5;
    o[0] = (float)img; o[1] = 0.f; o[2] = 0.f; o[3] = 0.f; o[4] = 0.f;
  }
}

extern "C" void kernel_launch(void* const* d_in, const int* in_sizes, int n_in,
                              void* d_out, int out_size, void* d_ws, size_t ws_size,
                              hipStream_t stream) {
  const float* sm   = (const float*)d_in[0];
  const float* bd   = (const float*)d_in[1];
  const float* info = (const float*)d_in[2];
  float* out = (float*)d_out;
  char* ws = (char*)d_ws;

  size_t off = 0;
  auto alloc = [&](size_t bytes) { size_t o = off; off += (bytes + 255) & ~(size_t)255; return o; };
  u64* keys     = (u64*)(ws + alloc((size_t)NBATCH * NPB * 8));        // ~29.5 MB
  size_t off_hist = alloc((size_t)NBATCH * UNI_BINS * 4);              // 128 KB
  u32* hist     = (u32*)(ws + off_hist);
  u32* selcnt   = (u32*)(ws + alloc(NBATCH * 4));                      // adjacent to hist
  size_t zero_end = off;
  u64* thresh   = (u64*)(ws + alloc(NBATCH * 8));
  u32* nvalid   = (u32*)(ws + alloc(NBATCH * 4));
  u64* sel      = (u64*)(ws + alloc((size_t)NBATCH * SEL_CAP * 8));    // 1 MB
  float4* boxsel= (float4*)(ws + alloc((size_t)NBATCH * SEL_CAP * 16));// 2 MB
  float4* boxes = (float4*)(ws + alloc((size_t)NBATCH * PRE_N * 16));  // 1.5 MB
  (void)ws_size; (void)in_sizes; (void)n_in; (void)out_size;

  hipMemsetAsync(ws + off_hist, 0, zero_end - off_hist, stream);       // hist + selcnt
  hipLaunchKernelGGL(k_scores_hist, dim3(960), dim3(256), 0, stream, sm, bd, info, keys, hist);
  hipLaunchKernelGGL(k_select, dim3(16), dim3(256), 0, stream, keys, hist, thresh);
  hipLaunchKernelGGL(k_compact, dim3(60, 16), dim3(256), 0, stream, keys, thresh, selcnt, sel, bd, info, boxsel);
  hipLaunchKernelGGL(k_sort1, dim3(8, 16), dim3(256), 0, stream, sel, selcnt);
  hipLaunchKernelGGL(k_sort2, dim3(16), dim3(1024), 0, stream, sel, boxsel, boxes, nvalid);
  hipLaunchKernelGGL(k_nms, dim3(16), dim3(512), 0, stream, boxes, nvalid, out);
}